// Round 5
// baseline (407.726 us; speedup 1.0000x reference)
//
#include <hip/hip_runtime.h>

typedef short s16x8 __attribute__((ext_vector_type(8)));
typedef float f32x4 __attribute__((ext_vector_type(4)));

#define N_SAMPLES 65536
#define DIM 768
#define HID 384
#define NEXP 8
#define NCLS 8
#define JT 24   // HID/16
#define KT 24   // DIM/32

// workspace layout (bytes)
#define WS_CNT    0
#define WS_BUCKET 1024
#define WS_W1F    (WS_BUCKET + NEXP * N_SAMPLES * 4)     // 2,098,176
#define WS_W2T    (WS_W1F + NEXP * JT * KT * 64 * 8 * 2) // 6,816,768
// W2T: NEXP*16*HID*2 = 98,304 -> total 6,915,072 (~6.9 MB)

// RNE bf16 (prep only)
__device__ __forceinline__ unsigned short f2bf(float f) {
  union { float f; unsigned u; } v; v.f = f;
  unsigned r = v.u + 0x7fffu + ((v.u >> 16) & 1u);
  return (unsigned short)(r >> 16);
}

// fast half-up pair: 2x v_add + 1x v_perm = 1.5 VALU/element
// result: low16 = bf(a), high16 = bf(b)
__device__ __forceinline__ unsigned cvt2(float a, float b) {
  union { float f; unsigned u; } ua, ub;
  ua.f = a; ub.f = b;
  return __builtin_amdgcn_perm(ub.u + 0x8000u, ua.u + 0x8000u, 0x07060302u);
}

// lgkm-only barrier: does NOT drain vmcnt (global prefetches stay in flight)
#define LBAR asm volatile("s_waitcnt lgkmcnt(0)\n\ts_barrier" ::: "memory")

// W1[e][k=768][j=384] f32 -> W1F in MFMA A-fragment order:
// W1F[((e*JT+jt)*KT+kt)*64 + lane][i] = W1[e][kt*32+(lane>>4)*8+i][jt*16+(lane&15)]
__global__ void k_w1frag(const float* __restrict__ W1,
                         unsigned short* __restrict__ W1F,
                         int* __restrict__ cnt) {
  if (blockIdx.x == 0 && blockIdx.y == 0 && threadIdx.x < NEXP)
    cnt[threadIdx.x] = 0;
  const int e = blockIdx.x;
  const int unit = blockIdx.y * 4 + (threadIdx.x >> 6);   // (jt,kt) flat, 0..575
  const int lane = threadIdx.x & 63;
  const int jt = unit / KT, kt = unit % KT;
  const int j = jt * 16 + (lane & 15);
  const int k0 = kt * 32 + (lane >> 4) * 8;
  const float* src = W1 + ((size_t)e * DIM + k0) * HID + j;
  s16x8 v;
#pragma unroll
  for (int i = 0; i < 8; ++i) v[i] = (short)f2bf(src[(size_t)i * HID]);
  *(s16x8*)&W1F[(((size_t)e * JT * KT + unit) * 64 + lane) * 8] = v;
}

// blocks 0..255: bucket rows by expert
// blocks 256..263: W2[e][j][c] -> W2T[e][c(16, rows 8..15 zero)][j=384] bf16
__global__ void k_scatter(const int* __restrict__ qt, const float* __restrict__ W2,
                          int* __restrict__ cnt, int* __restrict__ bucket,
                          unsigned short* __restrict__ W2T) {
  const int t = threadIdx.x;
  if (blockIdx.x >= 256) {
    const int e = blockIdx.x - 256;
    for (int j = t; j < HID; j += 256) {
#pragma unroll
      for (int c = 0; c < NCLS; ++c)
        W2T[((size_t)e * 16 + c) * HID + j] = f2bf(W2[((size_t)e * HID + j) * NCLS + c]);
#pragma unroll
      for (int c = NCLS; c < 16; ++c) W2T[((size_t)e * 16 + c) * HID + j] = 0;
    }
    return;
  }
  __shared__ int lcnt[NEXP], lbase[NEXP];
  const int i = blockIdx.x * 256 + t;
  if (t < NEXP) lcnt[t] = 0;
  __syncthreads();
  const int e = qt[i];
  const int rank = atomicAdd(&lcnt[e], 1);
  __syncthreads();
  if (t < NEXP) lbase[t] = atomicAdd(&cnt[t], lcnt[t]);
  __syncthreads();
  bucket[(size_t)e * N_SAMPLES + lbase[e] + rank] = i;
}

// per-lane direct x fragment loads for k-step KS (B-operand gather, 16B x2)
#define XLOAD(BUF, KS)                                                    \
  _Pragma("unroll") for (int mi = 0; mi < 4; ++mi) {                      \
    const float4* p_ = (const float4*)(xp[mi] + (KS) * 32);               \
    BUF##lo[mi] = p_[0]; BUF##hi[mi] = p_[1];                             \
  }

// 6 coalesced b128 W1F fragment loads for k-step KS (L2-resident)
#define WLOAD(DST, KS)                                                    \
  _Pragma("unroll") for (int ni = 0; ni < 6; ++ni)                        \
      DST[ni] = *(const s16x8*)(wfbase + ((size_t)ni * KT + (KS)) * 512);

// cvt x regs -> bf16 B-frag, 24 MFMA. No LDS, no barrier.
#define COMPUTE(XB, WF)                                                   \
  _Pragma("unroll") for (int mi = 0; mi < 4; ++mi) {                      \
    unsigned q0 = cvt2(XB##lo[mi].x, XB##lo[mi].y);                       \
    unsigned q1 = cvt2(XB##lo[mi].z, XB##lo[mi].w);                       \
    unsigned q2 = cvt2(XB##hi[mi].x, XB##hi[mi].y);                       \
    unsigned q3 = cvt2(XB##hi[mi].z, XB##hi[mi].w);                       \
    union { uint4 u; s16x8 s; } xf_; xf_.u = (uint4){q0, q1, q2, q3};     \
    _Pragma("unroll") for (int ni = 0; ni < 6; ++ni)                      \
        acc[mi][ni] = __builtin_amdgcn_mfma_f32_16x16x32_bf16(            \
            WF[ni], xf_.s, acc[mi][ni], 0, 0, 0);                         \
  }

// block = (expert e -> pinned XCD, 64 gathered rows, all 384 H)
// K-loop: zero LDS, zero barriers; operands stream from L1/L2 into MFMA.
__global__ __launch_bounds__(256, 2) void k_moe_gemm(
    const float* __restrict__ x, const unsigned short* __restrict__ W1F,
    const float* __restrict__ b1, const unsigned short* __restrict__ W2T,
    const float* __restrict__ b2, const int* __restrict__ cnt,
    const int* __restrict__ bucket, float* __restrict__ out) {
  __shared__ __align__(16) short Hs[64 * 392];   // 50,176 B, sole LDS use
  const int e = blockIdx.x;
  const int n_e = cnt[e];
  const int t = threadIdx.x;
  const int lane = t & 63;
  const int wave = t >> 6;
  const int lrow = lane & 15;
  const int quad = lane >> 4;

  // this wave's W1F base: jt = wave*6 + ni, per-kt stride 512 shorts
  const unsigned short* wfbase =
      W1F + ((size_t)(e * JT + wave * 6) * KT) * 512 + lane * 8;

  for (int rt = blockIdx.y; rt * 64 < n_e; rt += gridDim.y) {
    const int row0 = rt * 64;
    LBAR;   // prev tile's epi-2 Hs reads done (no-op cost on first iter)

    // per-lane x row pointers for the 4 m-tiles (row = mi*16 + lrow)
    const float* xp[4];
#pragma unroll
    for (int mi = 0; mi < 4; ++mi) {
      int slot = row0 + mi * 16 + lrow;
      if (slot >= n_e) slot = n_e - 1;        // clamp: dup compute, masked store
      xp[mi] = x + (size_t)bucket[(size_t)e * N_SAMPLES + slot] * DIM + quad * 8;
    }

    f32x4 acc[4][6];
#pragma unroll
    for (int mi = 0; mi < 4; ++mi)
#pragma unroll
      for (int ni = 0; ni < 6; ++ni) acc[mi][ni] = (f32x4){0.f, 0.f, 0.f, 0.f};

    float4 Alo[4], Ahi[4], Blo[4], Bhi[4];
    s16x8 wfA[6], wfB[6];
    XLOAD(A, 0) WLOAD(wfA, 0)
    XLOAD(B, 1) WLOAD(wfB, 1)

    for (int ks = 0; ks < 24; ks += 2) {
      COMPUTE(A, wfA)
      if (ks + 2 < 24) { XLOAD(A, ks + 2) WLOAD(wfA, ks + 2) }
      COMPUTE(B, wfB)
      if (ks + 3 < 24) { XLOAD(B, ks + 3) WLOAD(wfB, ks + 3) }
    }

    // epilogue 1: bias+relu -> Hs[m][j]; acc: col(lane&15)=m, rows(quad*4+r)=j
    // b1 read directly from global (L1-hot); 4 consecutive j -> ds_write_b64
#pragma unroll
    for (int ni = 0; ni < 6; ++ni) {
      const float4 bb = *(const float4*)(b1 + e * HID + wave * 96 + ni * 16 + quad * 4);
#pragma unroll
      for (int mi = 0; mi < 4; ++mi) {
        float v0 = acc[mi][ni][0] + bb.x; v0 = v0 > 0.f ? v0 : 0.f;
        float v1 = acc[mi][ni][1] + bb.y; v1 = v1 > 0.f ? v1 : 0.f;
        float v2 = acc[mi][ni][2] + bb.z; v2 = v2 > 0.f ? v2 : 0.f;
        float v3 = acc[mi][ni][3] + bb.w; v3 = v3 > 0.f ? v3 : 0.f;
        uint2 pk = {cvt2(v0, v1), cvt2(v2, v3)};
        *(uint2*)&Hs[(mi * 16 + lrow) * 392 + wave * 96 + ni * 16 + quad * 4] = pk;
      }
    }
    LBAR;   // the ONLY structural barrier: Hs visible for layer 2

    // epilogue 2: layer-2 MFMA, M=64 (m-tile = wave), N=16 (8 valid), K=384
    // W2T B-frags read directly from global (12 KB, L1/L2-resident)
    {
      f32x4 acc2 = (f32x4){0.f, 0.f, 0.f, 0.f};
      const unsigned short* w2p = W2T + ((size_t)e * 16 + lrow) * HID + quad * 8;
#pragma unroll
      for (int kk = 0; kk < 12; ++kk) {
        s16x8 af = *(const s16x8*)&Hs[(wave * 16 + lrow) * 392 + kk * 32 + quad * 8];
        s16x8 bf = *(const s16x8*)(w2p + kk * 32);
        acc2 = __builtin_amdgcn_mfma_f32_16x16x32_bf16(af, bf, acc2, 0, 0, 0);
      }
      if (lrow < NCLS) {
        const float bb = b2[e * NCLS + lrow];
#pragma unroll
        for (int r = 0; r < 4; ++r) {
          const int m = wave * 16 + quad * 4 + r;
          if (row0 + m < n_e) {
            const int oi = bucket[(size_t)e * N_SAMPLES + row0 + m];
            out[(size_t)oi * NCLS + lrow] = acc2[r] + bb;
          }
        }
      }
    }
  }
}

extern "C" void kernel_launch(void* const* d_in, const int* in_sizes, int n_in,
                              void* d_out, int out_size, void* d_ws, size_t ws_size,
                              hipStream_t stream) {
  const float* x  = (const float*)d_in[0];
  const float* W1 = (const float*)d_in[1];
  const float* b1 = (const float*)d_in[2];
  const float* W2 = (const float*)d_in[3];
  const float* b2 = (const float*)d_in[4];
  const int* qt   = (const int*)d_in[5];
  float* out = (float*)d_out;
  char* ws = (char*)d_ws;

  int* cnt = (int*)(ws + WS_CNT);
  int* bucket = (int*)(ws + WS_BUCKET);
  unsigned short* W1F = (unsigned short*)(ws + WS_W1F);
  unsigned short* W2T = (unsigned short*)(ws + WS_W2T);

  k_w1frag<<<dim3(8, 144), dim3(256), 0, stream>>>(W1, W1F, cnt);
  k_scatter<<<dim3(264), dim3(256), 0, stream>>>(qt, W2, cnt, bucket, W2T);
  // y=144: covers n_e up to 9216 in one pass; rt-loop is the safety net
  k_moe_gemm<<<dim3(8, 144), dim3(256), 0, stream>>>(x, W1F, b1, W2T, b2, cnt, bucket, out);
}